// Round 5
// baseline (95.268 us; speedup 1.0000x reference)
//
#include <hip/hip_runtime.h>

// MultiHeadAttention_3753801417043 — MI355X/gfx950
// B=32, S=512, D_IN=128, N_HEAD=8, DIM_MODEL=512, SCALE=8.
//   W_eff[k][n] = sum_h W[h*128+k][n]  (concat([x]*8)@W == x@W_eff)
//   Q/K/V = x @ W_eff + b     3-pass split-bf16 MFMA, bf16-hi output
//   fused attention v2:       512 blocks × 32 q-rows, 2 blocks/CU,
//                             swapped QK^T (S^T), read→barrier→stage→MFMA pipeline

typedef unsigned short u16;
typedef __attribute__((ext_vector_type(8))) short bf16x8;
typedef __attribute__((ext_vector_type(4))) float f32x4;
typedef __attribute__((ext_vector_type(2))) float f32x2;
typedef __attribute__((ext_vector_type(2))) unsigned int u32x2;

__device__ inline u16 f2bf(float f) {            // round-to-nearest-even fp32->bf16
  unsigned u = __float_as_uint(f);
  u = u + 0x7fffu + ((u >> 16) & 1u);
  return (u16)(u >> 16);
}
__device__ inline float bf2f(u16 h) { return __uint_as_float(((unsigned)h) << 16); }

// async global->LDS, 16B per lane (wave-uniform LDS base + lane*16; linear layout)
__device__ inline void gl16(const u16* g, u16* l) {
  __builtin_amdgcn_global_load_lds(
      (const __attribute__((address_space(1))) unsigned int*)g,
      (__attribute__((address_space(3))) unsigned int*)l, 16, 0, 0);
}

// ---- W_eff prep, LDS-transposed: coalesced reads, 16B coalesced writes ----
__global__ __launch_bounds__(256)
void prep_w(const float* __restrict__ Wq, const float* __restrict__ Wk,
            const float* __restrict__ Wv,
            u16* __restrict__ WTh, u16* __restrict__ WTl) {
  __shared__ float sm[128][17];
  int t  = blockIdx.x >> 5;
  int nb = blockIdx.x & 31;
  const float* W = (t == 0) ? Wq : (t == 1) ? Wk : Wv;
  int n0 = nb << 4;
  int nl = threadIdx.x & 15;
  int kq = threadIdx.x >> 4;
  float s[8];
#pragma unroll
  for (int i = 0; i < 8; ++i) s[i] = 0.f;
#pragma unroll
  for (int h = 0; h < 8; ++h)
#pragma unroll
    for (int i = 0; i < 8; ++i)
      s[i] += W[(h * 128 + kq + (i << 4)) * 512 + n0 + nl];
#pragma unroll
  for (int i = 0; i < 8; ++i) sm[kq + (i << 4)][nl] = s[i];
  __syncthreads();
  int no = threadIdx.x >> 4;
  int k8 = (threadIdx.x & 15) << 3;
  bf16x8 h8, l8;
#pragma unroll
  for (int c = 0; c < 8; ++c) {
    float v = sm[k8 + c][no];
    u16 h = f2bf(v);
    h8[c] = (short)h;
    l8[c] = (short)f2bf(v - bf2f(h));
  }
  long o = (long)t * 65536 + (long)(n0 + no) * 128 + k8;
  *(bf16x8*)&WTh[o] = h8;
  *(bf16x8*)&WTl[o] = l8;
}

// ---- x split into bf16 hi/lo ----
__global__ __launch_bounds__(256)
void split_x(const float* __restrict__ x, u16* __restrict__ xh, u16* __restrict__ xl) {
  int i = blockIdx.x * 256 + threadIdx.x;
  const f32x4* xx = (const f32x4*)x;
  f32x4 a = xx[i * 2], b = xx[i * 2 + 1];
  float v[8] = {a[0], a[1], a[2], a[3], b[0], b[1], b[2], b[3]};
  bf16x8 h8, l8;
#pragma unroll
  for (int j = 0; j < 8; ++j) {
    u16 h = f2bf(v[j]);
    h8[j] = (short)h;
    l8[j] = (short)f2bf(v[j] - bf2f(h));
  }
  ((bf16x8*)xh)[i] = h8;
  ((bf16x8*)xl)[i] = l8;
}

// ---- fused Q/K/V projection: 3-pass split-bf16, coalesced bf16 epilogue ----
__global__ __launch_bounds__(256, 2)
void proj_fused(const u16* __restrict__ xh, const u16* __restrict__ xl,
                const u16* __restrict__ WTh, const u16* __restrict__ WTl,
                u16* __restrict__ Qh, u16* __restrict__ Kh, u16* __restrict__ Vh,
                const float* __restrict__ bq, const float* __restrict__ bk,
                const float* __restrict__ bv) {
  __shared__ __align__(16) char ldsraw[65536];
  u16* st = (u16*)ldsraw;

  int tid = threadIdx.x;
  int bid = blockIdx.x;
  bid = (bid & 7) * 192 + (bid >> 3);          // XCD swizzle (1536 = 8×192)
  int which = bid % 3;
  int tile  = bid / 3;
  int mt = tile >> 2;
  int nt = tile & 3;

  const u16* Ah = xh + (long)mt * (128 * 128);
  const u16* Al = xl + (long)mt * (128 * 128);
  const u16* Bh = WTh + which * 65536 + nt * 16384;
  const u16* Bl = WTl + which * 65536 + nt * 16384;
  const float* bias = (which == 0) ? bq : (which == 1) ? bk : bv;
  u16* C = (which == 0) ? Qh : (which == 1) ? Kh : Vh;

  int lane = tid & 63;
  int wv = tid >> 6;
  int wm = (wv >> 1) << 6;
  int wn = (wv & 1) << 6;
  int frow = lane & 15;
  int fk = (lane >> 4) << 3;

  f32x4 acc[4][4];
#pragma unroll
  for (int i = 0; i < 4; ++i)
#pragma unroll
    for (int j = 0; j < 4; ++j) {
      f32x4 z = {0.f, 0.f, 0.f, 0.f};
      acc[i][j] = z;
    }

  for (int kk = 0; kk < 2; ++kk) {
    int k0 = kk << 6;
#pragma unroll
    for (int j = 0; j < 4; ++j) {
      int c = j * 256 + tid;
      int row = c >> 3;
      int scol = ((c & 7) ^ (row & 7)) << 3;
      int ga = row * 128 + k0 + scol;
      int lo = c << 3;
      gl16(Ah + ga, st + lo);
      gl16(Al + ga, st + 8192 + lo);
      gl16(Bh + ga, st + 16384 + lo);
      gl16(Bl + ga, st + 24576 + lo);
    }
    __syncthreads();
#pragma unroll
    for (int ks = 0; ks < 2; ++ks) {
      int kb = (ks << 5) + fk;
      bf16x8 a_h[4], a_l[4], b_h[4], b_l[4];
#pragma unroll
      for (int i = 0; i < 4; ++i) {
        int ar = wm + (i << 4) + frow;
        int ao = ar * 64 + (kb ^ ((ar & 7) << 3));
        a_h[i] = *(const bf16x8*)&st[ao];
        a_l[i] = *(const bf16x8*)&st[8192 + ao];
        int br = wn + (i << 4) + frow;
        int bo = br * 64 + (kb ^ ((br & 7) << 3));
        b_h[i] = *(const bf16x8*)&st[16384 + bo];
        b_l[i] = *(const bf16x8*)&st[24576 + bo];
      }
#pragma unroll
      for (int i = 0; i < 4; ++i)
#pragma unroll
        for (int j = 0; j < 4; ++j) {
          acc[i][j] = __builtin_amdgcn_mfma_f32_16x16x32_bf16(a_h[i], b_h[j], acc[i][j], 0, 0, 0);
          acc[i][j] = __builtin_amdgcn_mfma_f32_16x16x32_bf16(a_l[i], b_h[j], acc[i][j], 0, 0, 0);
          acc[i][j] = __builtin_amdgcn_mfma_f32_16x16x32_bf16(a_h[i], b_l[j], acc[i][j], 0, 0, 0);
        }
    }
    __syncthreads();
  }

  // Coalesced epilogue via per-wave fp32 LDS transpose (intra-wave, no barrier)
  float* tr = ((float*)ldsraw) + wv * 2112;
  int lr = lane >> 3;
  int c8 = (lane & 7) << 3;
  int colbase = (nt << 7) + wn + c8;
  float bb[8];
#pragma unroll
  for (int c = 0; c < 8; ++c) bb[c] = bias[colbase + c];
  long rowg0 = (long)(mt << 7) + wm;
#pragma unroll
  for (int q = 0; q < 2; ++q) {
#pragma unroll
    for (int il = 0; il < 2; ++il) {
      int i = (q << 1) + il;
#pragma unroll
      for (int j = 0; j < 4; ++j)
#pragma unroll
        for (int r = 0; r < 4; ++r)
          tr[((il << 4) + ((lane >> 4) << 2) + r) * 66 + (j << 4) + (lane & 15)] =
              acc[i][j][r];
    }
#pragma unroll
    for (int p = 0; p < 4; ++p) {
      int rr = (p << 3) + lr;
      float v[8];
      *(f32x2*)&v[0] = *(const f32x2*)&tr[rr * 66 + c8];
      *(f32x2*)&v[2] = *(const f32x2*)&tr[rr * 66 + c8 + 2];
      *(f32x2*)&v[4] = *(const f32x2*)&tr[rr * 66 + c8 + 4];
      *(f32x2*)&v[6] = *(const f32x2*)&tr[rr * 66 + c8 + 6];
      bf16x8 o8;
#pragma unroll
      for (int c = 0; c < 8; ++c) o8[c] = (short)f2bf(v[c] + bb[c]);
      *(bf16x8*)&C[(rowg0 + (q << 5) + rr) * 512 + colbase] = o8;
    }
  }
}

// ---- fused attention v2: 512 blocks (32 batches × 16 jb of 32 q-rows), 256 thr ----
// LDS 66KB -> 2 blocks/CU. Phase1: S^T = K·Q^T (swapped MFMA); softmax with 2-shfl
// row reduce; P bf16 in LDS; V-tile0 prefetched under softmax; phase2: OUT = V·P^T.
// Per k-step: {barrier; frag reads->regs; barrier; issue next stage; MFMA(regs)}.
__global__ __launch_bounds__(256, 2)
void attn_fused(const u16* __restrict__ Q, const u16* __restrict__ K,
                const u16* __restrict__ V, float* __restrict__ OUT) {
  __shared__ __align__(16) char LDS[67584];
  u16* stg = (u16*)LDS;                 // 32KB: K/V tile [512 rows][32 bf16], chunk-swz
  u16* qt  = (u16*)(LDS + 32768);       // 2KB: Q tile [32][32] (phase1) / scratch
  float* smax = (float*)(LDS + 32768);  //   512B: per-row per-wave max
  float* ssum = (float*)(LDS + 33280);  //   512B: per-row per-wave sum
  char* Pb = LDS + 34816;               // 32KB: P [32 rows][512 cols] bf16, ^((row&7)<<4)

  int tid = threadIdx.x;
  int p = blockIdx.x;
  int xcd = p & 7, sq = p >> 3;
  int b  = (xcd << 2) + (sq >> 4);      // 4 batches per XCD (4MB K+V = L2)
  int jb = sq & 15;

  const u16* Qp = Q + ((long)b * 512 + jb * 32) * 512;
  const u16* Kp = K + (long)b * 262144;
  const u16* Vp = V + (long)b * 262144;

  int lane = tid & 63, nw = tid >> 6;
  int frow = lane & 15, hi4 = lane >> 4;

  // stage [512 rows][cols k0..k0+32): 2048 16B-chunks, 8/thread; chunk-swz (row>>1)&3
  auto stageKV = [&](const u16* src, int k0) {
#pragma unroll
    for (int j = 0; j < 8; ++j) {
      int c = (j << 8) + tid;
      int row = c >> 2, cc = c & 3;
      int sc = (cc ^ ((row >> 1) & 3)) << 3;
      gl16(src + (long)row * 512 + k0 + sc, stg + (c << 3));
    }
  };
  auto stageQ = [&](int k0) {
    if (tid < 128) {
      int row = tid >> 2, cc = tid & 3;
      int sc = (cc ^ ((row >> 1) & 3)) << 3;
      gl16(Qp + (long)row * 512 + k0 + sc, qt + (tid << 3));
    }
  };

  // ---------------- phase 1: S^T = K·Q^T ----------------
  // wave nw: attn-cols [nw*128, +128) (8 A-frags from K), 32 q-rows (2 B-frags from Q)
  // acc[j][i]: col(lane&15)=q-row i*16+frow; row = attn-col nw*128+j*16+hi4*4+r
  f32x4 acc[8][2];
#pragma unroll
  for (int j = 0; j < 8; ++j)
#pragma unroll
    for (int i = 0; i < 2; ++i) {
      f32x4 z = {0.f, 0.f, 0.f, 0.f};
      acc[j][i] = z;
    }

  stageKV(Kp, 0);
  stageQ(0);

  for (int kk = 0; kk < 16; ++kk) {
    __syncthreads();                       // stage(kk) complete
    bf16x8 a[8], bq_[2];
#pragma unroll
    for (int j = 0; j < 8; ++j) {
      int R = (nw << 7) + (j << 4) + frow;
      int cc = hi4 ^ ((R >> 1) & 3);
      a[j] = *(const bf16x8*)&stg[(R << 5) + (cc << 3)];
    }
#pragma unroll
    for (int i = 0; i < 2; ++i) {
      int R = (i << 4) + frow;
      int cc = hi4 ^ ((R >> 1) & 3);
      bq_[i] = *(const bf16x8*)&qt[(R << 5) + (cc << 3)];
    }
    __syncthreads();                       // all reads done; buffer free
    if (kk < 15) {
      int k0 = (kk + 1) << 5;
      stageKV(Kp, k0);
      stageQ(k0);
    } else {
      stageKV(Vp, 0);                      // prefetch V tile 0 under softmax
    }
#pragma unroll
    for (int j = 0; j < 8; ++j)
#pragma unroll
      for (int i = 0; i < 2; ++i)
        acc[j][i] = __builtin_amdgcn_mfma_f32_16x16x32_bf16(a[j], bq_[i], acc[j][i], 0, 0, 0);
  }

  // ---------------- softmax over attn-cols (512) per q-row ----------------
  float mx[2];
#pragma unroll
  for (int i = 0; i < 2; ++i) {
    float m = acc[0][i][0];
#pragma unroll
    for (int j = 0; j < 8; ++j)
#pragma unroll
      for (int r = 0; r < 4; ++r) m = fmaxf(m, acc[j][i][r]);
    m = fmaxf(m, __shfl_xor(m, 16));
    m = fmaxf(m, __shfl_xor(m, 32));
    mx[i] = m;
  }
  if (hi4 == 0) {
#pragma unroll
    for (int i = 0; i < 2; ++i) smax[(((i << 4) + frow) << 2) + nw] = mx[i];
  }
  __syncthreads();
  float mf[2], sm_[2];
#pragma unroll
  for (int i = 0; i < 2; ++i) {
    f32x4 m4 = *(const f32x4*)&smax[((i << 4) + frow) << 2];
    mf[i] = fmaxf(fmaxf(m4[0], m4[1]), fmaxf(m4[2], m4[3]));
    sm_[i] = 0.f;
  }
#pragma unroll
  for (int j = 0; j < 8; ++j)
#pragma unroll
    for (int i = 0; i < 2; ++i)
#pragma unroll
      for (int r = 0; r < 4; ++r) {
        float pv = __expf((acc[j][i][r] - mf[i]) * 0.125f);   // fold /8 scale
        acc[j][i][r] = pv;
        sm_[i] += pv;
      }
#pragma unroll
  for (int i = 0; i < 2; ++i) {
    sm_[i] += __shfl_xor(sm_[i], 16);
    sm_[i] += __shfl_xor(sm_[i], 32);
  }
  if (hi4 == 0) {
#pragma unroll
    for (int i = 0; i < 2; ++i) ssum[(((i << 4) + frow) << 2) + nw] = sm_[i];
  }
  __syncthreads();
  float inv_[2];
#pragma unroll
  for (int i = 0; i < 2; ++i) {
    f32x4 s4 = *(const f32x4*)&ssum[((i << 4) + frow) << 2];
    inv_[i] = 1.f / (s4[0] + s4[1] + s4[2] + s4[3]);
  }
  // write P: per (i,j) 4 consecutive attn-cols at one q-row -> packed b64
#pragma unroll
  for (int i = 0; i < 2; ++i) {
    int qrow = (i << 4) + frow;
#pragma unroll
    for (int j = 0; j < 8; ++j) {
      int col0 = (nw << 7) + (j << 4) + (hi4 << 2);
      unsigned lo = (unsigned)f2bf(acc[j][i][0] * inv_[i]) |
                    ((unsigned)f2bf(acc[j][i][1] * inv_[i]) << 16);
      unsigned hi = (unsigned)f2bf(acc[j][i][2] * inv_[i]) |
                    ((unsigned)f2bf(acc[j][i][3] * inv_[i]) << 16);
      u32x2 w = {lo, hi};
      int byt = ((qrow << 10) + (col0 << 1)) ^ ((qrow & 7) << 4);
      *(u32x2*)(Pb + byt) = w;
    }
  }
  __syncthreads();   // P visible; V tile 0 staged (vmcnt drained)

  // ---------------- phase 2: OUT = V·P^T ----------------
  // wave nw: v-rows [nw*128, +128) (8 A-frags from V), 32 q-cols (2 B-frags from P)
  f32x4 o[8][2];
#pragma unroll
  for (int j = 0; j < 8; ++j)
#pragma unroll
    for (int i = 0; i < 2; ++i) {
      f32x4 z = {0.f, 0.f, 0.f, 0.f};
      o[j][i] = z;
    }

  for (int kk = 0; kk < 16; ++kk) {
    if (kk) __syncthreads();               // V(kk) staged
    int k0 = kk << 5;
    bf16x8 av[8], bp[2];
#pragma unroll
    for (int j = 0; j < 8; ++j) {
      int R = (nw << 7) + (j << 4) + frow;
      int cc = hi4 ^ ((R >> 1) & 3);
      av[j] = *(const bf16x8*)&stg[(R << 5) + (cc << 3)];
    }
#pragma unroll
    for (int i = 0; i < 2; ++i) {
      int R = (i << 4) + frow;
      int byt = ((R << 10) + ((k0 + (hi4 << 3)) << 1)) ^ ((R & 7) << 4);
      bp[i] = *(const bf16x8*)(Pb + byt);
    }
    __syncthreads();                       // reads done; buffer free
    if (kk < 15) stageKV(Vp, (kk + 1) << 5);
#pragma unroll
    for (int j = 0; j < 8; ++j)
#pragma unroll
      for (int i = 0; i < 2; ++i)
        o[j][i] = __builtin_amdgcn_mfma_f32_16x16x32_bf16(av[j], bp[i], o[j][i], 0, 0, 0);
  }

  // epilogue: OUT[b, v-row, jb*32 + q-col]
  float* Ob = OUT + (long)b * 262144 + jb * 32;
#pragma unroll
  for (int j = 0; j < 8; ++j)
#pragma unroll
    for (int i = 0; i < 2; ++i)
#pragma unroll
      for (int r = 0; r < 4; ++r) {
        int vrow = (nw << 7) + (j << 4) + (hi4 << 2) + r;
        Ob[(long)vrow * 512 + (i << 4) + frow] = o[j][i][r];
      }
}

extern "C" void kernel_launch(void* const* d_in, const int* in_sizes, int n_in,
                              void* d_out, int out_size, void* d_ws, size_t ws_size,
                              hipStream_t stream) {
  const float* x  = (const float*)d_in[0];
  const float* Wq = (const float*)d_in[1];
  const float* bq = (const float*)d_in[2];
  const float* Wk = (const float*)d_in[3];
  const float* bk = (const float*)d_in[4];
  const float* Wv = (const float*)d_in[5];
  const float* bv = (const float*)d_in[6];
  float* out = (float*)d_out;

  char* ws = (char*)d_ws;
  size_t off = 0;
  auto alloc = [&](size_t bytes) -> char* {
    char* p = ws + off;
    off = (off + bytes + 255) & ~(size_t)255;
    return p;
  };
  u16* WTh = (u16*)alloc((size_t)3 * 512 * 128 * 2);
  u16* WTl = (u16*)alloc((size_t)3 * 512 * 128 * 2);
  u16* xh  = (u16*)alloc((size_t)16384 * 128 * 2);
  u16* xl  = (u16*)alloc((size_t)16384 * 128 * 2);
  u16* Qh  = (u16*)alloc((size_t)16384 * 512 * 2);
  u16* Kh  = (u16*)alloc((size_t)16384 * 512 * 2);
  u16* Vh  = (u16*)alloc((size_t)16384 * 512 * 2);

  prep_w<<<96, 256, 0, stream>>>(Wq, Wk, Wv, WTh, WTl);
  split_x<<<1024, 256, 0, stream>>>(x, xh, xl);
  proj_fused<<<1536, 256, 0, stream>>>(xh, xl, WTh, WTl, Qh, Kh, Vh, bq, bk, bv);
  attn_fused<<<512, 256, 0, stream>>>(Qh, Kh, Vh, out);
}

// Round 6
// 82.175 us; speedup vs baseline: 1.1593x; 1.1593x over previous
//
#include <hip/hip_runtime.h>

// MultiHeadAttention_3753801417043 — MI355X/gfx950
// B=32, S=512, D_IN=128, N_HEAD=8, DIM_MODEL=512, SCALE=8.
//   W_eff[k][n] = sum_h W[h*128+k][n]  (concat([x]*8)@W == x@W_eff)
//   Q/K/V = x @ W_eff + b     3-pass split-bf16 MFMA, bf16-hi output
//   fused attention v3:       256 blocks × 64 q-rows, double-buffered 32KB chunks,
//                             one barrier/chunk, stage(c+1) overlaps reads+MFMA(c)

typedef unsigned short u16;
typedef __attribute__((ext_vector_type(8))) short bf16x8;
typedef __attribute__((ext_vector_type(4))) float f32x4;
typedef __attribute__((ext_vector_type(2))) float f32x2;
typedef __attribute__((ext_vector_type(2))) unsigned int u32x2;

__device__ inline u16 f2bf(float f) {            // round-to-nearest-even fp32->bf16
  unsigned u = __float_as_uint(f);
  u = u + 0x7fffu + ((u >> 16) & 1u);
  return (u16)(u >> 16);
}
__device__ inline float bf2f(u16 h) { return __uint_as_float(((unsigned)h) << 16); }

// async global->LDS, 16B per lane (wave-uniform LDS base + lane*16; linear layout)
__device__ inline void gl16(const u16* g, u16* l) {
  __builtin_amdgcn_global_load_lds(
      (const __attribute__((address_space(1))) unsigned int*)g,
      (__attribute__((address_space(3))) unsigned int*)l, 16, 0, 0);
}

// ---- W_eff prep, LDS-transposed: coalesced reads, 16B coalesced writes ----
__global__ __launch_bounds__(256)
void prep_w(const float* __restrict__ Wq, const float* __restrict__ Wk,
            const float* __restrict__ Wv,
            u16* __restrict__ WTh, u16* __restrict__ WTl) {
  __shared__ float sm[128][17];
  int t  = blockIdx.x >> 5;
  int nb = blockIdx.x & 31;
  const float* W = (t == 0) ? Wq : (t == 1) ? Wk : Wv;
  int n0 = nb << 4;
  int nl = threadIdx.x & 15;
  int kq = threadIdx.x >> 4;
  float s[8];
#pragma unroll
  for (int i = 0; i < 8; ++i) s[i] = 0.f;
#pragma unroll
  for (int h = 0; h < 8; ++h)
#pragma unroll
    for (int i = 0; i < 8; ++i)
      s[i] += W[(h * 128 + kq + (i << 4)) * 512 + n0 + nl];
#pragma unroll
  for (int i = 0; i < 8; ++i) sm[kq + (i << 4)][nl] = s[i];
  __syncthreads();
  int no = threadIdx.x >> 4;
  int k8 = (threadIdx.x & 15) << 3;
  bf16x8 h8, l8;
#pragma unroll
  for (int c = 0; c < 8; ++c) {
    float v = sm[k8 + c][no];
    u16 h = f2bf(v);
    h8[c] = (short)h;
    l8[c] = (short)f2bf(v - bf2f(h));
  }
  long o = (long)t * 65536 + (long)(n0 + no) * 128 + k8;
  *(bf16x8*)&WTh[o] = h8;
  *(bf16x8*)&WTl[o] = l8;
}

// ---- x split into bf16 hi/lo ----
__global__ __launch_bounds__(256)
void split_x(const float* __restrict__ x, u16* __restrict__ xh, u16* __restrict__ xl) {
  int i = blockIdx.x * 256 + threadIdx.x;
  const f32x4* xx = (const f32x4*)x;
  f32x4 a = xx[i * 2], b = xx[i * 2 + 1];
  float v[8] = {a[0], a[1], a[2], a[3], b[0], b[1], b[2], b[3]};
  bf16x8 h8, l8;
#pragma unroll
  for (int j = 0; j < 8; ++j) {
    u16 h = f2bf(v[j]);
    h8[j] = (short)h;
    l8[j] = (short)f2bf(v[j] - bf2f(h));
  }
  ((bf16x8*)xh)[i] = h8;
  ((bf16x8*)xl)[i] = l8;
}

// ---- fused Q/K/V projection: 3-pass split-bf16, coalesced bf16 epilogue ----
__global__ __launch_bounds__(256, 2)
void proj_fused(const u16* __restrict__ xh, const u16* __restrict__ xl,
                const u16* __restrict__ WTh, const u16* __restrict__ WTl,
                u16* __restrict__ Qh, u16* __restrict__ Kh, u16* __restrict__ Vh,
                const float* __restrict__ bq, const float* __restrict__ bk,
                const float* __restrict__ bv) {
  __shared__ __align__(16) char ldsraw[65536];
  u16* st = (u16*)ldsraw;

  int tid = threadIdx.x;
  int bid = blockIdx.x;
  bid = (bid & 7) * 192 + (bid >> 3);          // XCD swizzle (1536 = 8×192)
  int which = bid % 3;
  int tile  = bid / 3;
  int mt = tile >> 2;
  int nt = tile & 3;

  const u16* Ah = xh + (long)mt * (128 * 128);
  const u16* Al = xl + (long)mt * (128 * 128);
  const u16* Bh = WTh + which * 65536 + nt * 16384;
  const u16* Bl = WTl + which * 65536 + nt * 16384;
  const float* bias = (which == 0) ? bq : (which == 1) ? bk : bv;
  u16* C = (which == 0) ? Qh : (which == 1) ? Kh : Vh;

  int lane = tid & 63;
  int wv = tid >> 6;
  int wm = (wv >> 1) << 6;
  int wn = (wv & 1) << 6;
  int frow = lane & 15;
  int fk = (lane >> 4) << 3;

  f32x4 acc[4][4];
#pragma unroll
  for (int i = 0; i < 4; ++i)
#pragma unroll
    for (int j = 0; j < 4; ++j) {
      f32x4 z = {0.f, 0.f, 0.f, 0.f};
      acc[i][j] = z;
    }

  for (int kk = 0; kk < 2; ++kk) {
    int k0 = kk << 6;
#pragma unroll
    for (int j = 0; j < 4; ++j) {
      int c = j * 256 + tid;
      int row = c >> 3;
      int scol = ((c & 7) ^ (row & 7)) << 3;
      int ga = row * 128 + k0 + scol;
      int lo = c << 3;
      gl16(Ah + ga, st + lo);
      gl16(Al + ga, st + 8192 + lo);
      gl16(Bh + ga, st + 16384 + lo);
      gl16(Bl + ga, st + 24576 + lo);
    }
    __syncthreads();
#pragma unroll
    for (int ks = 0; ks < 2; ++ks) {
      int kb = (ks << 5) + fk;
      bf16x8 a_h[4], a_l[4], b_h[4], b_l[4];
#pragma unroll
      for (int i = 0; i < 4; ++i) {
        int ar = wm + (i << 4) + frow;
        int ao = ar * 64 + (kb ^ ((ar & 7) << 3));
        a_h[i] = *(const bf16x8*)&st[ao];
        a_l[i] = *(const bf16x8*)&st[8192 + ao];
        int br = wn + (i << 4) + frow;
        int bo = br * 64 + (kb ^ ((br & 7) << 3));
        b_h[i] = *(const bf16x8*)&st[16384 + bo];
        b_l[i] = *(const bf16x8*)&st[24576 + bo];
      }
#pragma unroll
      for (int i = 0; i < 4; ++i)
#pragma unroll
        for (int j = 0; j < 4; ++j) {
          acc[i][j] = __builtin_amdgcn_mfma_f32_16x16x32_bf16(a_h[i], b_h[j], acc[i][j], 0, 0, 0);
          acc[i][j] = __builtin_amdgcn_mfma_f32_16x16x32_bf16(a_l[i], b_h[j], acc[i][j], 0, 0, 0);
          acc[i][j] = __builtin_amdgcn_mfma_f32_16x16x32_bf16(a_h[i], b_l[j], acc[i][j], 0, 0, 0);
        }
    }
    __syncthreads();
  }

  // Coalesced epilogue via per-wave fp32 LDS transpose (intra-wave, no barrier)
  float* tr = ((float*)ldsraw) + wv * 2112;
  int lr = lane >> 3;
  int c8 = (lane & 7) << 3;
  int colbase = (nt << 7) + wn + c8;
  float bb[8];
#pragma unroll
  for (int c = 0; c < 8; ++c) bb[c] = bias[colbase + c];
  long rowg0 = (long)(mt << 7) + wm;
#pragma unroll
  for (int q = 0; q < 2; ++q) {
#pragma unroll
    for (int il = 0; il < 2; ++il) {
      int i = (q << 1) + il;
#pragma unroll
      for (int j = 0; j < 4; ++j)
#pragma unroll
        for (int r = 0; r < 4; ++r)
          tr[((il << 4) + ((lane >> 4) << 2) + r) * 66 + (j << 4) + (lane & 15)] =
              acc[i][j][r];
    }
#pragma unroll
    for (int p = 0; p < 4; ++p) {
      int rr = (p << 3) + lr;
      float v[8];
      *(f32x2*)&v[0] = *(const f32x2*)&tr[rr * 66 + c8];
      *(f32x2*)&v[2] = *(const f32x2*)&tr[rr * 66 + c8 + 2];
      *(f32x2*)&v[4] = *(const f32x2*)&tr[rr * 66 + c8 + 4];
      *(f32x2*)&v[6] = *(const f32x2*)&tr[rr * 66 + c8 + 6];
      bf16x8 o8;
#pragma unroll
      for (int c = 0; c < 8; ++c) o8[c] = (short)f2bf(v[c] + bb[c]);
      *(bf16x8*)&C[(rowg0 + (q << 5) + rr) * 512 + colbase] = o8;
    }
  }
}

// ---- fused attention v3 ----
// 256 blocks (32 batches × 8 jb of 64 q-rows), 512 threads, 1 block/CU.
// Chunks: [256 tokens][64 feat] = 32KB, rows = full 128B segments. Double-buffered,
// ONE barrier per chunk; stage(c+1) issued first, overlapping frag reads + MFMA(c).
// Swapped QK^T (S^T = K·Q^T) -> 2-shfl row reduce. P bf16 in LDS (64KB, XOR-swz).
__global__ __launch_bounds__(512, 1)
void attn_fused(const u16* __restrict__ Q, const u16* __restrict__ K,
                const u16* __restrict__ V, float* __restrict__ OUT) {
  __shared__ __align__(16) char LDS[151552];
  u16* B0  = (u16*)LDS;                  // 32KB chunk buf 0
  u16* B1  = (u16*)(LDS + 32768);        // 32KB chunk buf 1
  u16* P16 = (u16*)(LDS + 65536);        // 64KB P [64 q][512] bf16, byte ^ ((q&7)<<4)
  u16* QB0 = (u16*)(LDS + 131072);       // 8KB Q buf 0 [64 q][64 feat]
  u16* QB1 = (u16*)(LDS + 139264);       // 8KB Q buf 1
  float* smax = (float*)(LDS + 147456);  // [64][8]
  float* ssum = (float*)(LDS + 149504);  // [64][8]

  int tid = threadIdx.x;
  int p = blockIdx.x;
  int xcd = p & 7, sq = p >> 3;
  int b  = (xcd << 2) + (sq >> 3);       // 4 batches per XCD (K,V L2-resident)
  int jb = sq & 7;

  const u16* Qp = Q + ((long)b * 512 + jb * 64) * 512;
  const u16* Kp = K + (long)b * 262144;
  const u16* Vp = V + (long)b * 262144;

  int lane = tid & 63, nw = tid >> 6;
  int frow = lane & 15, hi4 = lane >> 4;

  // stage [256 rows][64 feat] from src half h at feat k0; 2048 16B units, 4/thread.
  // Source col pre-swizzled (slot ^= row&7); LDS dest linear (gl16 requirement).
  auto stageKV = [&](const u16* src, int h, int k0, u16* buf) {
#pragma unroll
    for (int j = 0; j < 4; ++j) {
      int u = (j << 9) + tid;
      int row = u >> 3, slot = u & 7;
      gl16(src + (long)((h << 8) + row) * 512 + k0 + ((slot ^ (row & 7)) << 3),
           buf + (u << 3));
    }
  };
  auto stageQ = [&](int k0, u16* qb) {   // [64 rows][64 feat], 512 units, 1/thread
    int row = tid >> 3, slot = tid & 7;
    gl16(Qp + (long)row * 512 + k0 + ((slot ^ (row & 7)) << 3), qb + (tid << 3));
  };
  // swizzled b128 frag read: row R, 16B-slot s (uniform spread across 8 slots)
  auto rf = [&](const u16* base, int R, int s) -> bf16x8 {
    return *(const bf16x8*)&base[(R << 6) + ((s ^ (R & 7)) << 3)];
  };

  f32x4 acc0[2][4], acc1[2][4];
#pragma unroll
  for (int jj = 0; jj < 2; ++jj)
#pragma unroll
    for (int ii = 0; ii < 4; ++ii) {
      f32x4 z = {0.f, 0.f, 0.f, 0.f};
      acc0[jj][ii] = z;
      acc1[jj][ii] = z;
    }

  // ---------------- phase 1: S^T = K·Q^T ----------------
  stageKV(Kp, 0, 0, B0);
  stageQ(0, QB0);
  __syncthreads();

  for (int k = 0; k < 8; ++k) {
    int k0 = k << 6;
    const u16* qc = (k & 1) ? QB1 : QB0;
    // chunk h=0 (tokens 0..255) from B0; stage h=1 into B1 first
    stageKV(Kp, 1, k0, B1);
    {
      bf16x8 af[2][2], qf[2][4];
#pragma unroll
      for (int ks = 0; ks < 2; ++ks) {
#pragma unroll
        for (int jj = 0; jj < 2; ++jj)
          af[ks][jj] = rf(B0, (nw << 5) + (jj << 4) + frow, (ks << 2) + hi4);
#pragma unroll
        for (int ii = 0; ii < 4; ++ii)
          qf[ks][ii] = rf(qc, (ii << 4) + frow, (ks << 2) + hi4);
      }
      __builtin_amdgcn_s_setprio(1);
#pragma unroll
      for (int ks = 0; ks < 2; ++ks)
#pragma unroll
        for (int jj = 0; jj < 2; ++jj)
#pragma unroll
          for (int ii = 0; ii < 4; ++ii)
            acc0[jj][ii] = __builtin_amdgcn_mfma_f32_16x16x32_bf16(af[ks][jj], qf[ks][ii], acc0[jj][ii], 0, 0, 0);
      __builtin_amdgcn_s_setprio(0);
    }
    __syncthreads();
    // chunk h=1 (tokens 256..511) from B1; stage next (h=0,k0+64)+Q into B0
    if (k < 7) { stageKV(Kp, 0, k0 + 64, B0); stageQ(k0 + 64, (k & 1) ? QB0 : QB1); }
    else stageKV(Vp, 0, 0, B0);            // prefetch V chunk 0 (drains in softmax)
    {
      bf16x8 af[2][2], qf[2][4];
#pragma unroll
      for (int ks = 0; ks < 2; ++ks) {
#pragma unroll
        for (int jj = 0; jj < 2; ++jj)
          af[ks][jj] = rf(B1, (nw << 5) + (jj << 4) + frow, (ks << 2) + hi4);
#pragma unroll
        for (int ii = 0; ii < 4; ++ii)
          qf[ks][ii] = rf(qc, (ii << 4) + frow, (ks << 2) + hi4);
      }
      __builtin_amdgcn_s_setprio(1);
#pragma unroll
      for (int ks = 0; ks < 2; ++ks)
#pragma unroll
        for (int jj = 0; jj < 2; ++jj)
#pragma unroll
          for (int ii = 0; ii < 4; ++ii)
            acc1[jj][ii] = __builtin_amdgcn_mfma_f32_16x16x32_bf16(af[ks][jj], qf[ks][ii], acc1[jj][ii], 0, 0, 0);
      __builtin_amdgcn_s_setprio(0);
    }
    if (k < 7) __syncthreads();
  }

  // ---------------- softmax per q-row over 512 attn-cols ----------------
  // lane holds q-rows ii*16+frow; its 16 values per ii: acc{0,1}[jj][ii][r]
  float mx[4], sm[4], inv_[4];
#pragma unroll
  for (int ii = 0; ii < 4; ++ii) {
    float m = acc0[0][ii][0];
#pragma unroll
    for (int jj = 0; jj < 2; ++jj)
#pragma unroll
      for (int r = 0; r < 4; ++r) {
        m = fmaxf(m, acc0[jj][ii][r]);
        m = fmaxf(m, acc1[jj][ii][r]);
      }
    m = fmaxf(m, __shfl_xor(m, 16));
    m = fmaxf(m, __shfl_xor(m, 32));
    mx[ii] = m;
  }
  __syncthreads();                       // also drains V-chunk-0 stage
  if (hi4 == 0) {
#pragma unroll
    for (int ii = 0; ii < 4; ++ii) smax[(((ii << 4) + frow) << 3) + nw] = mx[ii];
  }
  __syncthreads();
#pragma unroll
  for (int ii = 0; ii < 4; ++ii) {
    f32x4 a = *(const f32x4*)&smax[((ii << 4) + frow) << 3];
    f32x4 c = *(const f32x4*)&smax[(((ii << 4) + frow) << 3) + 4];
    mx[ii] = fmaxf(fmaxf(fmaxf(a[0], a[1]), fmaxf(a[2], a[3])),
                   fmaxf(fmaxf(c[0], c[1]), fmaxf(c[2], c[3])));
    sm[ii] = 0.f;
  }
#pragma unroll
  for (int jj = 0; jj < 2; ++jj)
#pragma unroll
    for (int ii = 0; ii < 4; ++ii)
#pragma unroll
      for (int r = 0; r < 4; ++r) {
        float p0 = __expf((acc0[jj][ii][r] - mx[ii]) * 0.125f);
        float p1 = __expf((acc1[jj][ii][r] - mx[ii]) * 0.125f);
        acc0[jj][ii][r] = p0;
        acc1[jj][ii][r] = p1;
        sm[ii] += p0 + p1;
      }
#pragma unroll
  for (int ii = 0; ii < 4; ++ii) {
    sm[ii] += __shfl_xor(sm[ii], 16);
    sm[ii] += __shfl_xor(sm[ii], 32);
  }
  if (hi4 == 0) {
#pragma unroll
    for (int ii = 0; ii < 4; ++ii) ssum[(((ii << 4) + frow) << 3) + nw] = sm[ii];
  }
  __syncthreads();
#pragma unroll
  for (int ii = 0; ii < 4; ++ii) {
    f32x4 a = *(const f32x4*)&ssum[((ii << 4) + frow) << 3];
    f32x4 c = *(const f32x4*)&ssum[(((ii << 4) + frow) << 3) + 4];
    inv_[ii] = 1.f / (a[0] + a[1] + a[2] + a[3] + c[0] + c[1] + c[2] + c[3]);
  }
  // write P [64 q][512], byte-XOR ((qrow&7)<<4), packed b64 per 4 attn-cols
#pragma unroll
  for (int ii = 0; ii < 4; ++ii) {
    int qr = (ii << 4) + frow;
    int rowoff = qr << 10;
    int swz = (qr & 7) << 4;
#pragma unroll
    for (int jj = 0; jj < 2; ++jj) {
      int c0 = ((nw << 5) + (jj << 4) + (hi4 << 2)) << 1;
      unsigned lo0 = (unsigned)f2bf(acc0[jj][ii][0] * inv_[ii]) |
                     ((unsigned)f2bf(acc0[jj][ii][1] * inv_[ii]) << 16);
      unsigned hi0 = (unsigned)f2bf(acc0[jj][ii][2] * inv_[ii]) |
                     ((unsigned)f2bf(acc0[jj][ii][3] * inv_[ii]) << 16);
      u32x2 w0 = {lo0, hi0};
      *(u32x2*)(LDS + 65536 + ((rowoff + c0) ^ swz)) = w0;
      unsigned lo1 = (unsigned)f2bf(acc1[jj][ii][0] * inv_[ii]) |
                     ((unsigned)f2bf(acc1[jj][ii][1] * inv_[ii]) << 16);
      unsigned hi1 = (unsigned)f2bf(acc1[jj][ii][2] * inv_[ii]) |
                     ((unsigned)f2bf(acc1[jj][ii][3] * inv_[ii]) << 16);
      u32x2 w1 = {lo1, hi1};
      *(u32x2*)(LDS + 65536 + ((rowoff + 512 + c0) ^ swz)) = w1;
    }
  }
  __syncthreads();                       // P visible; V chunk 0 staged

  // ---------------- phase 2: OUT = V·P^T ----------------
  f32x4 o0[2][4], o1[2][4];
#pragma unroll
  for (int jj = 0; jj < 2; ++jj)
#pragma unroll
    for (int ii = 0; ii < 4; ++ii) {
      f32x4 z = {0.f, 0.f, 0.f, 0.f};
      o0[jj][ii] = z;
      o1[jj][ii] = z;
    }

  for (int k = 0; k < 8; ++k) {
    int k0 = k << 6;
    // chunk h=0 (v-rows 0..255) from B0; stage h=1 into B1
    stageKV(Vp, 1, k0, B1);
    {
      bf16x8 vf[2][2], pf[2][4];
#pragma unroll
      for (int ks = 0; ks < 2; ++ks) {
#pragma unroll
        for (int jj = 0; jj < 2; ++jj)
          vf[ks][jj] = rf(B0, (nw << 5) + (jj << 4) + frow, (ks << 2) + hi4);
#pragma unroll
        for (int ii = 0; ii < 4; ++ii) {
          int qr = (ii << 4) + frow;
          pf[ks][ii] = *(const bf16x8*)&P16[((qr << 9) + k0 + (ks << 5) + (hi4 << 3)) ^ ((qr & 7) << 3)];
        }
      }
      __builtin_amdgcn_s_setprio(1);
#pragma unroll
      for (int ks = 0; ks < 2; ++ks)
#pragma unroll
        for (int jj = 0; jj < 2; ++jj)
#pragma unroll
          for (int ii = 0; ii < 4; ++ii)
            o0[jj][ii] = __builtin_amdgcn_mfma_f32_16x16x32_bf16(vf[ks][jj], pf[ks][ii], o0[jj][ii], 0, 0, 0);
      __builtin_amdgcn_s_setprio(0);
    }
    __syncthreads();
    // chunk h=1 (v-rows 256..511) from B1; stage next h=0 into B0
    if (k < 7) stageKV(Vp, 0, k0 + 64, B0);
    {
      bf16x8 vf[2][2], pf[2][4];
#pragma unroll
      for (int ks = 0; ks < 2; ++ks) {
#pragma unroll
        for (int jj = 0; jj < 2; ++jj)
          vf[ks][jj] = rf(B1, (nw << 5) + (jj << 4) + frow, (ks << 2) + hi4);
#pragma unroll
        for (int ii = 0; ii < 4; ++ii) {
          int qr = (ii << 4) + frow;
          pf[ks][ii] = *(const bf16x8*)&P16[((qr << 9) + k0 + (ks << 5) + (hi4 << 3)) ^ ((qr & 7) << 3)];
        }
      }
      __builtin_amdgcn_s_setprio(1);
#pragma unroll
      for (int ks = 0; ks < 2; ++ks)
#pragma unroll
        for (int jj = 0; jj < 2; ++jj)
#pragma unroll
          for (int ii = 0; ii < 4; ++ii)
            o1[jj][ii] = __builtin_amdgcn_mfma_f32_16x16x32_bf16(vf[ks][jj], pf[ks][ii], o1[jj][ii], 0, 0, 0);
      __builtin_amdgcn_s_setprio(0);
    }
    if (k < 7) __syncthreads();
  }

  // epilogue: OUT[b, vrow, jb*64 + qcol]
  float* Ob = OUT + (long)b * 262144 + jb * 64;
#pragma unroll
  for (int jj = 0; jj < 2; ++jj)
#pragma unroll
    for (int ii = 0; ii < 4; ++ii)
#pragma unroll
      for (int r = 0; r < 4; ++r) {
        int vr = (nw << 5) + (jj << 4) + (hi4 << 2) + r;
        int qc = (ii << 4) + frow;
        Ob[(long)vr * 512 + qc] = o0[jj][ii][r];
        Ob[(long)(vr + 256) * 512 + qc] = o1[jj][ii][r];
      }
}

extern "C" void kernel_launch(void* const* d_in, const int* in_sizes, int n_in,
                              void* d_out, int out_size, void* d_ws, size_t ws_size,
                              hipStream_t stream) {
  const float* x  = (const float*)d_in[0];
  const float* Wq = (const float*)d_in[1];
  const float* bq = (const float*)d_in[2];
  const float* Wk = (const float*)d_in[3];
  const float* bk = (const float*)d_in[4];
  const float* Wv = (const float*)d_in[5];
  const float* bv = (const float*)d_in[6];
  float* out = (float*)d_out;

  char* ws = (char*)d_ws;
  size_t off = 0;
  auto alloc = [&](size_t bytes) -> char* {
    char* p = ws + off;
    off = (off + bytes + 255) & ~(size_t)255;
    return p;
  };
  u16* WTh = (u16*)alloc((size_t)3 * 512 * 128 * 2);
  u16* WTl = (u16*)alloc((size_t)3 * 512 * 128 * 2);
  u16* xh  = (u16*)alloc((size_t)16384 * 128 * 2);
  u16* xl  = (u16*)alloc((size_t)16384 * 128 * 2);
  u16* Qh  = (u16*)alloc((size_t)16384 * 512 * 2);
  u16* Kh  = (u16*)alloc((size_t)16384 * 512 * 2);
  u16* Vh  = (u16*)alloc((size_t)16384 * 512 * 2);

  prep_w<<<96, 256, 0, stream>>>(Wq, Wk, Wv, WTh, WTl);
  split_x<<<1024, 256, 0, stream>>>(x, xh, xl);
  proj_fused<<<1536, 256, 0, stream>>>(xh, xl, WTh, WTl, Qh, Kh, Vh, bq, bk, bv);
  attn_fused<<<256, 512, 0, stream>>>(Qh, Kh, Vh, out);
}